// Round 13
// baseline (560.958 us; speedup 1.0000x reference)
//
#include <hip/hip_runtime.h>

typedef unsigned short u16;
typedef __attribute__((ext_vector_type(4))) float f32x4;
typedef __attribute__((ext_vector_type(8))) short bf16x8;
typedef __attribute__((ext_vector_type(8))) unsigned short u16x8;
typedef __attribute__((ext_vector_type(4))) unsigned short u16x4;

__device__ __forceinline__ u16 f2bf(float f) {
  union { float f; unsigned u; } v; v.f = f;
  unsigned r = v.u + 0x7FFFu + ((v.u >> 16) & 1u);
  return (u16)(r >> 16);
}
__device__ __forceinline__ float bf2f(u16 h) {
  union { unsigned u; float f; } v; v.u = ((unsigned)h) << 16; return v.f;
}

__device__ __forceinline__ void gload_lds16(const void* g, void* l) {
  __builtin_amdgcn_global_load_lds((const __attribute__((address_space(1))) void*)g,
                                   (__attribute__((address_space(3))) void*)l, 16, 0, 0);
}

// ---------------- prep kernels ----------------

__global__ void k_zero(u16x8* __restrict__ p, int n8) {
  int i = blockIdx.x * blockDim.x + threadIdx.x;
  int stride = gridDim.x * blockDim.x;
  u16x8 z = (u16x8)0;
  for (; i < n8; i += stride) p[i] = z;
}

__global__ void k_cvt_x(const float* __restrict__ in, u16* __restrict__ out, int n4) {
  int i = blockIdx.x * blockDim.x + threadIdx.x;
  int stride = gridDim.x * blockDim.x;
  const f32x4* in4 = (const f32x4*)in;
  u16x4* out4 = (u16x4*)out;
  for (; i < n4; i += stride) {
    f32x4 v = in4[i];
    u16x4 o;
    o[0] = f2bf(v[0]); o[1] = f2bf(v[1]); o[2] = f2bf(v[2]); o[3] = f2bf(v[3]);
    out4[i] = o;
  }
}

// LDS-tiled transpose: w [K][1024] f32 -> outT [1024][K] bf16, 64x64 tiles.
__global__ void k_prep_wt(const float* __restrict__ wq, const float* __restrict__ wo,
                          const float* __restrict__ wk, const float* __restrict__ wv,
                          u16* __restrict__ WQ1T, u16* __restrict__ WO1T,
                          u16* __restrict__ WK1T, u16* __restrict__ WV1T) {
  __shared__ u16 tile[64][72];
  int bid = blockIdx.x;
  const float* w; u16* o; int K;
  if (bid < 256)      { w = wq; o = WQ1T; K = 1024; }
  else if (bid < 512) { w = wo; o = WO1T; K = 1024; bid -= 256; }
  else if (bid < 704) { w = wk; o = WK1T; K = 768;  bid -= 512; }
  else                { w = wv; o = WV1T; K = 768;  bid -= 704; }
  const int ti = bid >> 4, tj = bid & 15;
  const int t = threadIdx.x;
  const int r = t >> 2, cq = (t & 3) * 16;

  const float* src = w + (size_t)(ti * 64 + r) * 1024 + tj * 64 + cq;
#pragma unroll
  for (int j4 = 0; j4 < 4; ++j4) {
    f32x4 v = *(const f32x4*)(src + j4 * 4);
#pragma unroll
    for (int e = 0; e < 4; ++e) tile[r][cq + j4 * 4 + e] = f2bf(v[e]);
  }
  __syncthreads();

  u16 vals[16];
#pragma unroll
  for (int j = 0; j < 16; ++j) vals[j] = tile[cq + j][r];
  u16* dst = o + (size_t)(tj * 64 + r) * K + ti * 64 + cq;
  *(u16x8*)dst = *(u16x8*)&vals[0];
  *(u16x8*)(dst + 8) = *(u16x8*)&vals[8];
}

// y [1232][768] f32 -> yb bf16 (straight cvt)
__global__ void k_prep_y(const float* __restrict__ y, u16* __restrict__ yb, int n4) {
  int i = blockIdx.x * blockDim.x + threadIdx.x;
  int stride = gridDim.x * blockDim.x;
  const f32x4* in4 = (const f32x4*)y;
  u16x4* out4 = (u16x4*)yb;
  for (; i < n4; i += stride) {
    f32x4 v = in4[i];
    u16x4 o;
    o[0] = f2bf(v[0]); o[1] = f2bf(v[1]); o[2] = f2bf(v[2]); o[3] = f2bf(v[3]);
    out4[i] = o;
  }
}

// ---------------- K+V projections, merged, m97-style 128^2 ----------------
__global__ __launch_bounds__(256, 2) void k_gemm_kv(
    const u16* __restrict__ A,
    const u16* __restrict__ BK1, const float* __restrict__ bkb, u16* __restrict__ KTo,
    const u16* __restrict__ BV1, const float* __restrict__ bvb, u16* __restrict__ VTo)
{
  const int M = 1232, Kdim = 768;
  __shared__ u16 sA[128 * 32];
  __shared__ u16 sB[128 * 32];
  const int t = threadIdx.x;
  const int half = blockIdx.x >= 80;
  const int bb = blockIdx.x - half * 80;
  const u16* B = half ? BV1 : BK1;
  const float* bias = half ? bvb : bkb;
  u16* outp = half ? VTo : KTo;
  const int bm = bb / 8, bn = bb % 8;
  const int m0 = bm * 128, n0 = bn * 128;
  const int l = t & 63, wv_ = t >> 6;
  const int lr = l & 15, lg = l >> 4;
  const int wm = (wv_ >> 1) * 64, wn = (wv_ & 1) * 64;

  const int srow = t >> 2;
  const int ssw = ((t >> 2) & 3) ^ ((t >> 4) & 3);
  const int scol = ((t & 3) ^ ssw) * 8;
  char* ldsA = (char*)sA;
  char* ldsB = (char*)sB;
  const int ldsoff = wv_ * 1024;

  const int swl = (lr & 3) ^ ((lr >> 2) & 3);
  const int rds = (lg ^ swl) * 8;

  f32x4 acc[4][4] = {};

  for (int kt = 0; kt < Kdim / 32; ++kt) {
    const int k0 = kt * 32;
    __syncthreads();
    {
      int r1 = m0 + srow;       if (r1 > M - 1) r1 = M - 1;
      int r2 = m0 + 64 + srow;  if (r2 > M - 1) r2 = M - 1;
      gload_lds16(A + (size_t)r1 * Kdim + k0 + scol, ldsA + 0    + ldsoff);
      gload_lds16(A + (size_t)r2 * Kdim + k0 + scol, ldsA + 4096 + ldsoff);
      gload_lds16(B + (size_t)(n0 + srow) * Kdim + k0 + scol,      ldsB + 0    + ldsoff);
      gload_lds16(B + (size_t)(n0 + 64 + srow) * Kdim + k0 + scol, ldsB + 4096 + ldsoff);
    }
    __syncthreads();
    bf16x8 af[4], bfr[4];
#pragma unroll
    for (int mt = 0; mt < 4; ++mt)
      af[mt] = *(const bf16x8*)&sA[(wm + mt * 16 + lr) * 32 + rds];
#pragma unroll
    for (int nt = 0; nt < 4; ++nt)
      bfr[nt] = *(const bf16x8*)&sB[(wn + nt * 16 + lr) * 32 + rds];
#pragma unroll
    for (int mt = 0; mt < 4; ++mt)
#pragma unroll
      for (int nt = 0; nt < 4; ++nt)
        acc[mt][nt] = __builtin_amdgcn_mfma_f32_16x16x32_bf16(af[mt], bfr[nt], acc[mt][nt], 0, 0, 0);
  }

#pragma unroll
  for (int mt = 0; mt < 4; ++mt) {
#pragma unroll
    for (int nt = 0; nt < 4; ++nt) {
      const int gc = n0 + wn + nt * 16 + lr;
      const float bb2 = bias[gc];
#pragma unroll
      for (int r = 0; r < 4; ++r) {
        const int gr = m0 + wm + mt * 16 + lg * 4 + r;
        const float v = acc[mt][nt][r] + bb2;
        if (gr < M) {
          int bI = gr / 77, s = gr - bI * 77;
          int hh = gc >> 6, d = gc & 63;
          if (!half)
            outp[(((size_t)bI * 16 + hh) * 96 + s) * 64 + d] = f2bf(v);
          else
            outp[(((size_t)bI * 16 + hh) * 64 + d) * 96 + s] = f2bf(v);
        }
      }
    }
  }
}

// ---------------- big GEMM: 256x128, BK=64, r5's 0-conflict layout + r11's overlap ----------------
// M=65536, N=1024, K=1024. A [M][1024] bf16, B^T [1024][1024] bf16.
// 512 thr = 8 waves (4M x 2N), wave tile 64x64. 16 K-tiles of BK=64.
// LDS: 3 slots x (A 32KB + B 16KB) = 144KB. 128-byte rows + r5's sw16 XOR swizzle
// (measured ZERO bank conflicts in r5, vs 1.3e7 for all 64B-row variants).
// Overlap (r11): RD(tile c+1) issued after BAR, concurrent with MM(tile c) -- compiler
// emits counted lgkmcnt so LDS pipe (688cyc/CU/tile) runs under MFMA (1242cyc/CU/tile).
// Body c: STAGE(c+2):6 gloads ; vmcnt(6) ; BAR ; RD(c+1):16 ds_reads ; MM(c):32 MFMA ; BAR.
// Ledger: at vmcnt(6), outstanding = stage(c+1):6 + stage(c+2):6 -> retires c+1 exactly.
// Slot overwritten by STAGE(c+2) held tile c-1, consumed at body c-1 behind 2 barriers.
// EPI 0: fused attention epilogue (K/V frags hoisted ONCE -- r12 reloaded 4x, latency-bound).
// EPI 1: +bias -> f32.
template <int EPI>
__global__ __launch_bounds__(512, 2) void gemm256(
    const u16* __restrict__ A, const u16* __restrict__ Bp,
    const float* __restrict__ bias, void* __restrict__ outp,
    const u16* __restrict__ KT, const u16* __restrict__ VT)
{
  __shared__ char lds[147456];
  const int t = threadIdx.x;
  const int cpx = (int)gridDim.x >> 3;
  const int swz = ((int)blockIdx.x & 7) * cpx + ((int)blockIdx.x >> 3);
  const int bm = swz >> 3, bn = swz & 7;
  const int m0 = bm * 256, n0 = bn * 128;
  const int w = t >> 6, l = t & 63, lr = l & 15, lg = l >> 4;
  const int wm = w >> 1, wn = w & 1;   // 4 M-waves x 2 N-waves, wave tile 64x64
  const int wbase = w * 1024;

  // r5 staging/swizzle (verified 0 conflicts): per 64-row issue, row = t>>3,
  // 16B slot (t&7) ^ (row&7); read-side slot (kk*4+lg) ^ (lr&7).
  const int srow = t >> 3;
  const int scol = ((t & 7) ^ (srow & 7)) << 3;   // elems
  const int sw16_0 = ((lg) ^ (lr & 7)) << 4;
  const int sw16_1 = ((4 + lg) ^ (lr & 7)) << 4;
  const int arow = wm * 64 + lr;
  const int brow = wn * 64 + lr;

  f32x4 acc[4][4] = {};

#define RD(dstA, dstB, rbb) { \
  _Pragma("unroll") for (int q = 0; q < 4; ++q) { \
    dstA[q]     = *(const bf16x8*)(lds + (rbb) + ((arow + q * 16) << 7) + sw16_0); \
    dstA[4 + q] = *(const bf16x8*)(lds + (rbb) + ((arow + q * 16) << 7) + sw16_1); } \
  _Pragma("unroll") for (int nt = 0; nt < 4; ++nt) { \
    dstB[nt]     = *(const bf16x8*)(lds + (rbb) + 32768 + ((brow + nt * 16) << 7) + sw16_0); \
    dstB[4 + nt] = *(const bf16x8*)(lds + (rbb) + 32768 + ((brow + nt * 16) << 7) + sw16_1); } }
#define STAGE(kt, sbb) { \
  _Pragma("unroll") for (int j = 0; j < 4; ++j) \
    gload_lds16(A + (size_t)(m0 + j * 64 + srow) * 1024 + (kt) * 64 + scol, \
                lds + (sbb) + j * 8192 + wbase); \
  _Pragma("unroll") for (int j = 0; j < 2; ++j) \
    gload_lds16(Bp + (size_t)(n0 + j * 64 + srow) * 1024 + (kt) * 64 + scol, \
                lds + (sbb) + 32768 + j * 8192 + wbase); }
#define MM(a_, b_) { __builtin_amdgcn_s_setprio(1); \
  _Pragma("unroll") for (int kk = 0; kk < 2; ++kk) \
    _Pragma("unroll") for (int q = 0; q < 4; ++q) \
      _Pragma("unroll") for (int nt = 0; nt < 4; ++nt) \
        acc[q][nt] = __builtin_amdgcn_mfma_f32_16x16x32_bf16(a_[kk * 4 + q], b_[kk * 4 + nt], acc[q][nt], 0, 0, 0); \
  __builtin_amdgcn_s_setprio(0); }
#define BAR __builtin_amdgcn_s_barrier()
#define SB0 __builtin_amdgcn_sched_barrier(0)
#define VM6 asm volatile("s_waitcnt vmcnt(6)" ::: "memory")

  bf16x8 aA[8], bA[8], aB[8], bB[8];

  // prologue: stage tile0 -> slot0, tile1 -> slot1; vmcnt(6) retires tile0; read it.
  STAGE(0, 0);
  STAGE(1, 49152);
  VM6; SB0; BAR;
  RD(aA, bA, 0);

  int rdo = 49152, sto = 2 * 49152;
#pragma unroll 1
  for (int i = 0; i < 16; i += 2) {
    { // body A: tile i
      int ks = i + 2; if (ks > 15) ks = 15;
      STAGE(ks, sto); sto += 49152; if (sto == 147456) sto = 0;
      VM6; SB0; BAR;
      RD(aB, bB, rdo); rdo += 49152; if (rdo == 147456) rdo = 0;
      MM(aA, bA);
      BAR;
    }
    { // body B: tile i+1
      int ks = i + 3; if (ks > 15) ks = 15;
      STAGE(ks, sto); sto += 49152; if (sto == 147456) sto = 0;
      VM6; SB0; BAR;
      RD(aA, bA, rdo); rdo += 49152; if (rdo == 147456) rdo = 0;
      MM(aB, bB);
      BAR;
    }
  }
  asm volatile("s_waitcnt vmcnt(0)" ::: "memory");  // drain dummy stages
  SB0; BAR;                                          // LDS quiescent block-wide

#undef RD
#undef STAGE
#undef MM
#undef BAR
#undef SB0
#undef VM6

  if constexpr (EPI == 1) {
    // out-proj epilogue: +bias -> f32
#pragma unroll
    for (int q = 0; q < 4; ++q) {
#pragma unroll
      for (int nt = 0; nt < 4; ++nt) {
        const int gc = n0 + wn * 64 + nt * 16 + lr;
        const float bb = bias[gc];
#pragma unroll
        for (int r = 0; r < 4; ++r) {
          const int gr = m0 + wm * 64 + q * 16 + lg * 4 + r;
          ((float*)outp)[(size_t)gr * 1024 + gc] = acc[q][nt][r] + bb;
        }
      }
    }
  } else {
    // ---- fused attention epilogue (K/V frags hoisted once) ----
    const int hh = (n0 >> 6) + wn;          // this wave's head (64 cols = 1 head)
    const int b = m0 >> 12;                 // batch (256-row tile never straddles)
    const u16* gK = KT + (size_t)(b * 16 + hh) * (96 * 64);
    const u16* gV = VT + (size_t)(b * 16 + hh) * (64 * 96);
    u16* Qs = (u16*)(lds + w * 16384);          // [32][72]
    u16* Ps = (u16*)(lds + w * 16384 + 8192);   // [32][104]
    u16* QBo = (u16*)outp;

    // hoisted K frags (5 nt x 2 ks) and V frags (4 nt x 3 ks) -- chunk-invariant
    bf16x8 fk[5][2], fv[4][3];
#pragma unroll
    for (int nt = 0; nt < 5; ++nt)
#pragma unroll
      for (int ks = 0; ks < 2; ++ks)
        fk[nt][ks] = *(const bf16x8*)&gK[(nt * 16 + lr) * 64 + ks * 32 + lg * 8];
#pragma unroll
    for (int nt = 0; nt < 4; ++nt)
#pragma unroll
      for (int ks = 0; ks < 3; ++ks)
        fv[nt][ks] = *(const bf16x8*)&gV[(nt * 16 + lr) * 96 + ks * 32 + lg * 8];

    float bb[4];
#pragma unroll
    for (int nt = 0; nt < 4; ++nt) bb[nt] = bias[n0 + wn * 64 + nt * 16 + lr];

#pragma unroll
    for (int cc = 0; cc < 2; ++cc) {
      // 1. bias + cvt + write Q chunk (rows cc*32..+31) to wave-private LDS
#pragma unroll
      for (int qq = 0; qq < 2; ++qq)
#pragma unroll
        for (int nt = 0; nt < 4; ++nt)
#pragma unroll
          for (int r = 0; r < 4; ++r)
            Qs[(qq * 16 + lg * 4 + r) * 72 + nt * 16 + lr] =
                f2bf(acc[cc * 2 + qq][nt][r] + bb[nt]);

      // 2. Q A-frags (same-wave LDS RAW -> compiler lgkmcnt)
      bf16x8 aq[2][2];
#pragma unroll
      for (int qq = 0; qq < 2; ++qq)
#pragma unroll
        for (int ks = 0; ks < 2; ++ks)
          aq[qq][ks] = *(const bf16x8*)&Qs[(qq * 16 + lr) * 72 + ks * 32 + lg * 8];

      // 3. scores QK^T from hoisted K frags
      f32x4 s_[2][5] = {};
#pragma unroll
      for (int nt = 0; nt < 5; ++nt)
#pragma unroll
        for (int ks = 0; ks < 2; ++ks)
#pragma unroll
          for (int qq = 0; qq < 2; ++qq)
            s_[qq][nt] = __builtin_amdgcn_mfma_f32_16x16x32_bf16(aq[qq][ks], fk[nt][ks], s_[qq][nt], 0, 0, 0);
#pragma unroll
      for (int qq = 0; qq < 2; ++qq)
#pragma unroll
        for (int nt = 0; nt < 5; ++nt)
#pragma unroll
          for (int r = 0; r < 4; ++r)
            s_[qq][nt][r] *= 0.125f;
      if (lr >= 13) {
#pragma unroll
        for (int qq = 0; qq < 2; ++qq)
#pragma unroll
          for (int r = 0; r < 4; ++r)
            s_[qq][4][r] = -1e30f;
      }

      // 4. softmax per row (16-lane shuffle reduce)
      float ri[2][4];
#pragma unroll
      for (int qq = 0; qq < 2; ++qq) {
#pragma unroll
        for (int r = 0; r < 4; ++r) {
          float m1 = s_[qq][0][r];
#pragma unroll
          for (int nt = 1; nt < 5; ++nt) m1 = fmaxf(m1, s_[qq][nt][r]);
          m1 = fmaxf(m1, __shfl_xor(m1, 1, 64));
          m1 = fmaxf(m1, __shfl_xor(m1, 2, 64));
          m1 = fmaxf(m1, __shfl_xor(m1, 4, 64));
          m1 = fmaxf(m1, __shfl_xor(m1, 8, 64));
          float s1 = 0.f;
#pragma unroll
          for (int nt = 0; nt < 5; ++nt) {
            float e = __expf(s_[qq][nt][r] - m1);
            s_[qq][nt][r] = e;
            s1 += e;
          }
          s1 += __shfl_xor(s1, 1, 64);
          s1 += __shfl_xor(s1, 2, 64);
          s1 += __shfl_xor(s1, 4, 64);
          s1 += __shfl_xor(s1, 8, 64);
          ri[qq][r] = 1.0f / s1;
        }
      }

      // 5. P -> LDS (+ zero pad keys 80..95)
#pragma unroll
      for (int qq = 0; qq < 2; ++qq)
#pragma unroll
        for (int nt = 0; nt < 5; ++nt)
#pragma unroll
          for (int r = 0; r < 4; ++r)
            Ps[(qq * 16 + lg * 4 + r) * 104 + nt * 16 + lr] = f2bf(s_[qq][nt][r] * ri[qq][r]);
#pragma unroll
      for (int qq = 0; qq < 2; ++qq)
#pragma unroll
        for (int r = 0; r < 4; ++r)
          Ps[(qq * 16 + lg * 4 + r) * 104 + 80 + lr] = 0;

      // 6. PV from hoisted V frags
      f32x4 o_[2][4] = {};
#pragma unroll
      for (int ks = 0; ks < 3; ++ks) {
        bf16x8 ap[2];
#pragma unroll
        for (int qq = 0; qq < 2; ++qq)
          ap[qq] = *(const bf16x8*)&Ps[(qq * 16 + lr) * 104 + ks * 32 + lg * 8];
#pragma unroll
        for (int nt = 0; nt < 4; ++nt)
#pragma unroll
          for (int qq = 0; qq < 2; ++qq)
            o_[qq][nt] = __builtin_amdgcn_mfma_f32_16x16x32_bf16(ap[qq], fv[nt][ks], o_[qq][nt], 0, 0, 0);
      }

      // 7. attn-out -> QB
#pragma unroll
      for (int qq = 0; qq < 2; ++qq)
#pragma unroll
        for (int nt = 0; nt < 4; ++nt)
#pragma unroll
          for (int r = 0; r < 4; ++r)
            QBo[(size_t)(m0 + wm * 64 + cc * 32 + qq * 16 + lg * 4 + r) * 1024
                + hh * 64 + nt * 16 + lr] = f2bf(o_[qq][nt][r]);
    }
  }
}

// ---------------- launch ----------------

extern "C" void kernel_launch(void* const* d_in, const int* in_sizes, int n_in,
                              void* d_out, int out_size, void* d_ws, size_t ws_size,
                              hipStream_t stream) {
  const float* x  = (const float*)d_in[0];
  const float* y  = (const float*)d_in[1];
  const float* wq = (const float*)d_in[2];
  const float* bq = (const float*)d_in[3];
  const float* wk = (const float*)d_in[4];
  const float* bk = (const float*)d_in[5];
  const float* wv = (const float*)d_in[6];
  const float* bv = (const float*)d_in[7];
  const float* wo = (const float*)d_in[8];
  const float* bo = (const float*)d_in[9];

  char* ws = (char*)d_ws;
  u16* QB   = (u16*)(ws + 0);            // 65536x1024 bf16 = 128 MB (attn-out)
  u16* WQ1T = (u16*)(ws + 134217728);    // [1024][1024] bf16, 2 MB
  u16* WO1T = (u16*)(ws + 136314880);    // 2 MB
  u16* WK1T = (u16*)(ws + 138412032);    // [1024][768] bf16, 1.5 MB
  u16* WV1T = (u16*)(ws + 139984896);    // 1.5 MB
  u16* YB   = (u16*)(ws + 141557760);    // [1232][768] bf16, 1.85 MB
  u16* KT   = (u16*)(ws + 143654912);    // [16][16][96][64] bf16, 3 MB
  u16* VT   = (u16*)(ws + 146800640);    // [16][16][64][96] bf16, 3 MB

  u16*   XB  = (u16*)d_out;   // x as bf16, first 128 MB of d_out (consumed before final write)
  float* OUT = (float*)d_out;

  // prep
  k_zero<<<768, 256, 0, stream>>>((u16x8*)KT, 393216);          // zero KT+VT (adjacent, 6 MB)
  k_cvt_x<<<4096, 256, 0, stream>>>(x, XB, 16777216);
  k_prep_wt<<<896, 256, 0, stream>>>(wq, wo, wk, wv, WQ1T, WO1T, WK1T, WV1T);
  k_prep_y<<<924, 256, 0, stream>>>(y, YB, 236544);

  // K+V projections (one launch): M=1232, K=768
  k_gemm_kv<<<160, 256, 0, stream>>>(YB, WK1T, bk, KT, WV1T, bv, VT);

  // Q projection + FUSED ATTENTION -> QB; grid 256 bm x 8 bn
  gemm256<0><<<2048, 512, 0, stream>>>(XB, WQ1T, bq, QB, KT, VT);

  // output projection -> f32 d_out
  gemm256<1><<<2048, 512, 0, stream>>>(QB, WO1T, bo, OUT, nullptr, nullptr);
}

// Round 14
// 531.925 us; speedup vs baseline: 1.0546x; 1.0546x over previous
//
#include <hip/hip_runtime.h>

typedef unsigned short u16;
typedef __attribute__((ext_vector_type(4))) float f32x4;
typedef __attribute__((ext_vector_type(8))) short bf16x8;
typedef __attribute__((ext_vector_type(8))) unsigned short u16x8;
typedef __attribute__((ext_vector_type(4))) unsigned short u16x4;

__device__ __forceinline__ u16 f2bf(float f) {
  union { float f; unsigned u; } v; v.f = f;
  unsigned r = v.u + 0x7FFFu + ((v.u >> 16) & 1u);
  return (u16)(r >> 16);
}
__device__ __forceinline__ float bf2f(u16 h) {
  union { unsigned u; float f; } v; v.u = ((unsigned)h) << 16; return v.f;
}

__device__ __forceinline__ void gload_lds16(const void* g, void* l) {
  __builtin_amdgcn_global_load_lds((const __attribute__((address_space(1))) void*)g,
                                   (__attribute__((address_space(3))) void*)l, 16, 0, 0);
}

// ---------------- prep kernels ----------------

__global__ void k_zero(u16x8* __restrict__ p, int n8) {
  int i = blockIdx.x * blockDim.x + threadIdx.x;
  int stride = gridDim.x * blockDim.x;
  u16x8 z = (u16x8)0;
  for (; i < n8; i += stride) p[i] = z;
}

__global__ void k_cvt_x(const float* __restrict__ in, u16* __restrict__ out, int n4) {
  int i = blockIdx.x * blockDim.x + threadIdx.x;
  int stride = gridDim.x * blockDim.x;
  const f32x4* in4 = (const f32x4*)in;
  u16x4* out4 = (u16x4*)out;
  for (; i < n4; i += stride) {
    f32x4 v = in4[i];
    u16x4 o;
    o[0] = f2bf(v[0]); o[1] = f2bf(v[1]); o[2] = f2bf(v[2]); o[3] = f2bf(v[3]);
    out4[i] = o;
  }
}

// LDS-tiled transpose: w [K][1024] f32 -> outT [1024][K] bf16, 64x64 tiles.
__global__ void k_prep_wt(const float* __restrict__ wq, const float* __restrict__ wo,
                          const float* __restrict__ wk, const float* __restrict__ wv,
                          u16* __restrict__ WQ1T, u16* __restrict__ WO1T,
                          u16* __restrict__ WK1T, u16* __restrict__ WV1T) {
  __shared__ u16 tile[64][72];
  int bid = blockIdx.x;
  const float* w; u16* o; int K;
  if (bid < 256)      { w = wq; o = WQ1T; K = 1024; }
  else if (bid < 512) { w = wo; o = WO1T; K = 1024; bid -= 256; }
  else if (bid < 704) { w = wk; o = WK1T; K = 768;  bid -= 512; }
  else                { w = wv; o = WV1T; K = 768;  bid -= 704; }
  const int ti = bid >> 4, tj = bid & 15;
  const int t = threadIdx.x;
  const int r = t >> 2, cq = (t & 3) * 16;

  const float* src = w + (size_t)(ti * 64 + r) * 1024 + tj * 64 + cq;
#pragma unroll
  for (int j4 = 0; j4 < 4; ++j4) {
    f32x4 v = *(const f32x4*)(src + j4 * 4);
#pragma unroll
    for (int e = 0; e < 4; ++e) tile[r][cq + j4 * 4 + e] = f2bf(v[e]);
  }
  __syncthreads();

  u16 vals[16];
#pragma unroll
  for (int j = 0; j < 16; ++j) vals[j] = tile[cq + j][r];
  u16* dst = o + (size_t)(tj * 64 + r) * K + ti * 64 + cq;
  *(u16x8*)dst = *(u16x8*)&vals[0];
  *(u16x8*)(dst + 8) = *(u16x8*)&vals[8];
}

// y [1232][768] f32 -> yb bf16 (straight cvt)
__global__ void k_prep_y(const float* __restrict__ y, u16* __restrict__ yb, int n4) {
  int i = blockIdx.x * blockDim.x + threadIdx.x;
  int stride = gridDim.x * blockDim.x;
  const f32x4* in4 = (const f32x4*)y;
  u16x4* out4 = (u16x4*)yb;
  for (; i < n4; i += stride) {
    f32x4 v = in4[i];
    u16x4 o;
    o[0] = f2bf(v[0]); o[1] = f2bf(v[1]); o[2] = f2bf(v[2]); o[3] = f2bf(v[3]);
    out4[i] = o;
  }
}

// ---------------- K+V projections, merged, m97-style 128^2 ----------------
__global__ __launch_bounds__(256, 2) void k_gemm_kv(
    const u16* __restrict__ A,
    const u16* __restrict__ BK1, const float* __restrict__ bkb, u16* __restrict__ KTo,
    const u16* __restrict__ BV1, const float* __restrict__ bvb, u16* __restrict__ VTo)
{
  const int M = 1232, Kdim = 768;
  __shared__ u16 sA[128 * 32];
  __shared__ u16 sB[128 * 32];
  const int t = threadIdx.x;
  const int half = blockIdx.x >= 80;
  const int bb = blockIdx.x - half * 80;
  const u16* B = half ? BV1 : BK1;
  const float* bias = half ? bvb : bkb;
  u16* outp = half ? VTo : KTo;
  const int bm = bb / 8, bn = bb % 8;
  const int m0 = bm * 128, n0 = bn * 128;
  const int l = t & 63, wv_ = t >> 6;
  const int lr = l & 15, lg = l >> 4;
  const int wm = (wv_ >> 1) * 64, wn = (wv_ & 1) * 64;

  const int srow = t >> 2;
  const int ssw = ((t >> 2) & 3) ^ ((t >> 4) & 3);
  const int scol = ((t & 3) ^ ssw) * 8;
  char* ldsA = (char*)sA;
  char* ldsB = (char*)sB;
  const int ldsoff = wv_ * 1024;

  const int swl = (lr & 3) ^ ((lr >> 2) & 3);
  const int rds = (lg ^ swl) * 8;

  f32x4 acc[4][4] = {};

  for (int kt = 0; kt < Kdim / 32; ++kt) {
    const int k0 = kt * 32;
    __syncthreads();
    {
      int r1 = m0 + srow;       if (r1 > M - 1) r1 = M - 1;
      int r2 = m0 + 64 + srow;  if (r2 > M - 1) r2 = M - 1;
      gload_lds16(A + (size_t)r1 * Kdim + k0 + scol, ldsA + 0    + ldsoff);
      gload_lds16(A + (size_t)r2 * Kdim + k0 + scol, ldsA + 4096 + ldsoff);
      gload_lds16(B + (size_t)(n0 + srow) * Kdim + k0 + scol,      ldsB + 0    + ldsoff);
      gload_lds16(B + (size_t)(n0 + 64 + srow) * Kdim + k0 + scol, ldsB + 4096 + ldsoff);
    }
    __syncthreads();
    bf16x8 af[4], bfr[4];
#pragma unroll
    for (int mt = 0; mt < 4; ++mt)
      af[mt] = *(const bf16x8*)&sA[(wm + mt * 16 + lr) * 32 + rds];
#pragma unroll
    for (int nt = 0; nt < 4; ++nt)
      bfr[nt] = *(const bf16x8*)&sB[(wn + nt * 16 + lr) * 32 + rds];
#pragma unroll
    for (int mt = 0; mt < 4; ++mt)
#pragma unroll
      for (int nt = 0; nt < 4; ++nt)
        acc[mt][nt] = __builtin_amdgcn_mfma_f32_16x16x32_bf16(af[mt], bfr[nt], acc[mt][nt], 0, 0, 0);
  }

#pragma unroll
  for (int mt = 0; mt < 4; ++mt) {
#pragma unroll
    for (int nt = 0; nt < 4; ++nt) {
      const int gc = n0 + wn + nt * 16 + lr;
      const float bb2 = bias[gc];
#pragma unroll
      for (int r = 0; r < 4; ++r) {
        const int gr = m0 + wm + mt * 16 + lg * 4 + r;
        const float v = acc[mt][nt][r] + bb2;
        if (gr < M) {
          int bI = gr / 77, s = gr - bI * 77;
          int hh = gc >> 6, d = gc & 63;
          if (!half)
            outp[(((size_t)bI * 16 + hh) * 96 + s) * 64 + d] = f2bf(v);
          else
            outp[(((size_t)bI * 16 + hh) * 64 + d) * 96 + s] = f2bf(v);
        }
      }
    }
  }
}

// ---------------- big GEMM (r11 core, verbatim) + fused attention epilogue w/ hoisted K/V ----------------
// Main loop = r11 (passing, 183us/31%): 256x256, BK=32, 4-slot LDS ring, reg-dbuf read
// prefetch, vmcnt(8) ledger, XCD swizzle. ONE change vs r12 (251us): fk/fv fragments
// hoisted out of the chunk loop (chunk-invariant; r12 reloaded them 4x on the serial
// latency chain). Register budget at epilogue: acc 128 + fk 40 + fv 48 + temps < 256.
template <int EPI>
__global__ __launch_bounds__(512, 2) void gemm256(
    const u16* __restrict__ A, const u16* __restrict__ Bp,
    const float* __restrict__ bias, void* __restrict__ outp,
    const u16* __restrict__ KT, const u16* __restrict__ VT)
{
  __shared__ char lds[131072];
  const int t = threadIdx.x;
  const int cpx = (int)gridDim.x >> 3;
  const int swz = ((int)blockIdx.x & 7) * cpx + ((int)blockIdx.x >> 3);
  const int bm = swz >> 2, bn = swz & 3;
  const int m0 = bm * 256, n0 = bn * 256;
  const int w = t >> 6, l = t & 63, lr = l & 15, lg = l >> 4;
  const int wm = w >> 2, wn = w & 3;   // 2 M-waves x 4 N-waves, wave tile 128x64

  const int srow = t >> 2;
  const int scol = ((t & 3) ^ ((t >> 2) & 3) ^ ((t >> 4) & 3)) * 8;  // elems
  const int rsw = (lg ^ (lr & 3) ^ ((lr >> 2) & 3)) << 4;            // bytes
  const int arow = wm * 128 + lr;
  const int brow = wn * 64 + lr;

  f32x4 acc[8][4] = {};

#define RD(dstA, dstB, sbb) { \
  _Pragma("unroll") for (int q = 0; q < 8; ++q) \
    dstA[q] = *(const bf16x8*)(lds + (sbb) + ((arow + q * 16) << 6) + rsw); \
  _Pragma("unroll") for (int nt = 0; nt < 4; ++nt) \
    dstB[nt] = *(const bf16x8*)(lds + (sbb) + 16384 + ((brow + nt * 16) << 6) + rsw); }
#define STAGE(kt, sbb) { \
    gload_lds16(A  + (size_t)(m0 + srow) * 1024 + (kt) * 32 + scol,       lds + (sbb) + t * 16); \
    gload_lds16(A  + (size_t)(m0 + 128 + srow) * 1024 + (kt) * 32 + scol, lds + (sbb) + 8192 + t * 16); \
    gload_lds16(Bp + (size_t)(n0 + srow) * 1024 + (kt) * 32 + scol,       lds + (sbb) + 16384 + t * 16); \
    gload_lds16(Bp + (size_t)(n0 + 128 + srow) * 1024 + (kt) * 32 + scol, lds + (sbb) + 24576 + t * 16); }
#define MM(a_, b_) { __builtin_amdgcn_s_setprio(1); \
  _Pragma("unroll") for (int q = 0; q < 8; ++q) \
    _Pragma("unroll") for (int nt = 0; nt < 4; ++nt) \
      acc[q][nt] = __builtin_amdgcn_mfma_f32_16x16x32_bf16(a_[q], b_[nt], acc[q][nt], 0, 0, 0); \
  __builtin_amdgcn_s_setprio(0); }
#define BAR __builtin_amdgcn_s_barrier()
#define SB0 __builtin_amdgcn_sched_barrier(0)
#define VM8 asm volatile("s_waitcnt vmcnt(8)" ::: "memory")

  bf16x8 aA[8], bA[4], aB[8], bB[4];

  // prologue: stage tiles 0,1,2 into slots 0,1,2; vmcnt(8) retires tile 0; read it.
  STAGE(0, 0); STAGE(1, 32768); STAGE(2, 65536);
  VM8; SB0; BAR;
  RD(aA, bA, 0);

  int rdo = 32768, sto = 98304;
#pragma unroll 1
  for (int tt = 0; tt < 32; tt += 2) {
    { // body A: consume tile tt (aA/bA), prefetch-read tile tt+1 into aB/bB
      int ks = tt + 3; if (ks > 31) ks = 31;
      STAGE(ks, sto); sto = (sto + 32768) & 131071;
      VM8; SB0; BAR;
      RD(aB, bB, rdo); rdo = (rdo + 32768) & 131071;
      MM(aA, bA);
      BAR;
    }
    { // body B: consume tile tt+1 (aB/bB), prefetch-read tile tt+2 into aA/bA
      int ks = tt + 4; if (ks > 31) ks = 31;
      STAGE(ks, sto); sto = (sto + 32768) & 131071;
      VM8; SB0; BAR;
      RD(aA, bA, rdo); rdo = (rdo + 32768) & 131071;
      MM(aB, bB);
      BAR;
    }
  }
  asm volatile("s_waitcnt vmcnt(0)" ::: "memory");  // drain dummy stages
  SB0; BAR;                                          // ring quiescent block-wide

#undef RD
#undef STAGE
#undef MM
#undef BAR
#undef SB0
#undef VM8

  if constexpr (EPI == 1) {
    // out-proj epilogue: +bias -> f32
#pragma unroll
    for (int q = 0; q < 8; ++q) {
#pragma unroll
      for (int nt = 0; nt < 4; ++nt) {
        const int gc = n0 + wn * 64 + nt * 16 + lr;
        const float bb = bias[gc];
#pragma unroll
        for (int r = 0; r < 4; ++r) {
          const int gr = m0 + wm * 128 + q * 16 + lg * 4 + r;
          ((float*)outp)[(size_t)gr * 1024 + gc] = acc[q][nt][r] + bb;
        }
      }
    }
  } else {
    // ---- fused attention epilogue (K/V frags hoisted once — the r12 fix) ----
    const int hh = (n0 >> 6) + wn;          // head for this wave (64 cols = 1 head)
    const int b = m0 >> 12;                 // batch (256 rows never straddle)
    const u16* gK = KT + (size_t)(b * 16 + hh) * (96 * 64);
    const u16* gV = VT + (size_t)(b * 16 + hh) * (64 * 96);
    u16* Qs = (u16*)(lds + w * 16384);          // [32][72]
    u16* Ps = (u16*)(lds + w * 16384 + 8192);   // [32][104]
    u16* QBo = (u16*)outp;

    // hoisted, chunk-invariant fragments
    bf16x8 fk[5][2], fv[4][3];
#pragma unroll
    for (int nt = 0; nt < 5; ++nt)
#pragma unroll
      for (int ks = 0; ks < 2; ++ks)
        fk[nt][ks] = *(const bf16x8*)&gK[(nt * 16 + lr) * 64 + ks * 32 + lg * 8];
#pragma unroll
    for (int nt = 0; nt < 4; ++nt)
#pragma unroll
      for (int ks = 0; ks < 3; ++ks)
        fv[nt][ks] = *(const bf16x8*)&gV[(nt * 16 + lr) * 96 + ks * 32 + lg * 8];

    float bb[4];
#pragma unroll
    for (int nt = 0; nt < 4; ++nt) bb[nt] = bias[n0 + wn * 64 + nt * 16 + lr];

#pragma unroll
    for (int cc = 0; cc < 4; ++cc) {
      // 1. bias + cvt + write Q chunk (rows cc*32..+31) to wave-private LDS
#pragma unroll
      for (int qq = 0; qq < 2; ++qq)
#pragma unroll
        for (int nt = 0; nt < 4; ++nt)
#pragma unroll
          for (int r = 0; r < 4; ++r)
            Qs[(qq * 16 + lg * 4 + r) * 72 + nt * 16 + lr] =
                f2bf(acc[cc * 2 + qq][nt][r] + bb[nt]);

      // 2. Q A-frags (same-wave LDS RAW -> compiler lgkmcnt)
      bf16x8 aq[2][2];
#pragma unroll
      for (int qq = 0; qq < 2; ++qq)
#pragma unroll
        for (int ks = 0; ks < 2; ++ks)
          aq[qq][ks] = *(const bf16x8*)&Qs[(qq * 16 + lr) * 72 + ks * 32 + lg * 8];

      // 3. scores QK^T from hoisted K frags
      f32x4 s_[2][5] = {};
#pragma unroll
      for (int nt = 0; nt < 5; ++nt)
#pragma unroll
        for (int ks = 0; ks < 2; ++ks)
#pragma unroll
          for (int qq = 0; qq < 2; ++qq)
            s_[qq][nt] = __builtin_amdgcn_mfma_f32_16x16x32_bf16(aq[qq][ks], fk[nt][ks], s_[qq][nt], 0, 0, 0);
#pragma unroll
      for (int qq = 0; qq < 2; ++qq)
#pragma unroll
        for (int nt = 0; nt < 5; ++nt)
#pragma unroll
          for (int r = 0; r < 4; ++r)
            s_[qq][nt][r] *= 0.125f;
      if (lr >= 13) {
#pragma unroll
        for (int qq = 0; qq < 2; ++qq)
#pragma unroll
          for (int r = 0; r < 4; ++r)
            s_[qq][4][r] = -1e30f;
      }

      // 4. softmax per row (16-lane shuffle reduce)
      float ri[2][4];
#pragma unroll
      for (int qq = 0; qq < 2; ++qq) {
#pragma unroll
        for (int r = 0; r < 4; ++r) {
          float m1 = s_[qq][0][r];
#pragma unroll
          for (int nt = 1; nt < 5; ++nt) m1 = fmaxf(m1, s_[qq][nt][r]);
          m1 = fmaxf(m1, __shfl_xor(m1, 1, 64));
          m1 = fmaxf(m1, __shfl_xor(m1, 2, 64));
          m1 = fmaxf(m1, __shfl_xor(m1, 4, 64));
          m1 = fmaxf(m1, __shfl_xor(m1, 8, 64));
          float s1 = 0.f;
#pragma unroll
          for (int nt = 0; nt < 5; ++nt) {
            float e = __expf(s_[qq][nt][r] - m1);
            s_[qq][nt][r] = e;
            s1 += e;
          }
          s1 += __shfl_xor(s1, 1, 64);
          s1 += __shfl_xor(s1, 2, 64);
          s1 += __shfl_xor(s1, 4, 64);
          s1 += __shfl_xor(s1, 8, 64);
          ri[qq][r] = 1.0f / s1;
        }
      }

      // 5. P -> LDS (+ zero pad keys 80..95)
#pragma unroll
      for (int qq = 0; qq < 2; ++qq)
#pragma unroll
        for (int nt = 0; nt < 5; ++nt)
#pragma unroll
          for (int r = 0; r < 4; ++r)
            Ps[(qq * 16 + lg * 4 + r) * 104 + nt * 16 + lr] = f2bf(s_[qq][nt][r] * ri[qq][r]);
#pragma unroll
      for (int qq = 0; qq < 2; ++qq)
#pragma unroll
        for (int r = 0; r < 4; ++r)
          Ps[(qq * 16 + lg * 4 + r) * 104 + 80 + lr] = 0;

      // 6. PV from hoisted V frags
      f32x4 o_[2][4] = {};
#pragma unroll
      for (int ks = 0; ks < 3; ++ks) {
        bf16x8 ap[2];
#pragma unroll
        for (int qq = 0; qq < 2; ++qq)
          ap[qq] = *(const bf16x8*)&Ps[(qq * 16 + lr) * 104 + ks * 32 + lg * 8];
#pragma unroll
        for (int nt = 0; nt < 4; ++nt)
#pragma unroll
          for (int qq = 0; qq < 2; ++qq)
            o_[qq][nt] = __builtin_amdgcn_mfma_f32_16x16x32_bf16(ap[qq], fv[nt][ks], o_[qq][nt], 0, 0, 0);
      }

      // 7. attn-out -> QB
#pragma unroll
      for (int qq = 0; qq < 2; ++qq)
#pragma unroll
        for (int nt = 0; nt < 4; ++nt)
#pragma unroll
          for (int r = 0; r < 4; ++r)
            QBo[(size_t)(m0 + wm * 128 + cc * 32 + qq * 16 + lg * 4 + r) * 1024
                + hh * 64 + nt * 16 + lr] = f2bf(o_[qq][nt][r]);
    }
  }
}

// ---------------- launch ----------------

extern "C" void kernel_launch(void* const* d_in, const int* in_sizes, int n_in,
                              void* d_out, int out_size, void* d_ws, size_t ws_size,
                              hipStream_t stream) {
  const float* x  = (const float*)d_in[0];
  const float* y  = (const float*)d_in[1];
  const float* wq = (const float*)d_in[2];
  const float* bq = (const float*)d_in[3];
  const float* wk = (const float*)d_in[4];
  const float* bk = (const float*)d_in[5];
  const float* wv = (const float*)d_in[6];
  const float* bv = (const float*)d_in[7];
  const float* wo = (const float*)d_in[8];
  const float* bo = (const float*)d_in[9];

  char* ws = (char*)d_ws;
  u16* QB   = (u16*)(ws + 0);            // 65536x1024 bf16 = 128 MB (attn-out)
  u16* WQ1T = (u16*)(ws + 134217728);    // [1024][1024] bf16, 2 MB
  u16* WO1T = (u16*)(ws + 136314880);    // 2 MB
  u16* WK1T = (u16*)(ws + 138412032);    // [1024][768] bf16, 1.5 MB
  u16* WV1T = (u16*)(ws + 139984896);    // 1.5 MB
  u16* YB   = (u16*)(ws + 141557760);    // [1232][768] bf16, 1.85 MB
  u16* KT   = (u16*)(ws + 143654912);    // [16][16][96][64] bf16, 3 MB
  u16* VT   = (u16*)(ws + 146800640);    // [16][16][64][96] bf16, 3 MB

  u16*   XB  = (u16*)d_out;   // x as bf16, first 128 MB of d_out (consumed before final write)
  float* OUT = (float*)d_out;

  // prep
  k_zero<<<768, 256, 0, stream>>>((u16x8*)KT, 393216);          // zero KT+VT (adjacent, 6 MB)
  k_cvt_x<<<4096, 256, 0, stream>>>(x, XB, 16777216);
  k_prep_wt<<<896, 256, 0, stream>>>(wq, wo, wk, wv, WQ1T, WO1T, WK1T, WV1T);
  k_prep_y<<<924, 256, 0, stream>>>(y, YB, 236544);

  // K+V projections (one launch): M=1232, K=768
  k_gemm_kv<<<160, 256, 0, stream>>>(YB, WK1T, bk, KT, WV1T, bv, VT);

  // Q projection + FUSED ATTENTION -> QB
  gemm256<0><<<1024, 512, 0, stream>>>(XB, WQ1T, bq, QB, KT, VT);

  // output projection -> f32 d_out
  gemm256<1><<<1024, 512, 0, stream>>>(QB, WO1T, bo, OUT, nullptr, nullptr);
}

// Round 15
// 490.978 us; speedup vs baseline: 1.1425x; 1.0834x over previous
//
#include <hip/hip_runtime.h>

typedef unsigned short u16;
typedef __attribute__((ext_vector_type(4))) float f32x4;
typedef __attribute__((ext_vector_type(8))) short bf16x8;
typedef __attribute__((ext_vector_type(8))) unsigned short u16x8;
typedef __attribute__((ext_vector_type(4))) unsigned short u16x4;

__device__ __forceinline__ u16 f2bf(float f) {
  union { float f; unsigned u; } v; v.f = f;
  unsigned r = v.u + 0x7FFFu + ((v.u >> 16) & 1u);
  return (u16)(r >> 16);
}
__device__ __forceinline__ float bf2f(u16 h) {
  union { unsigned u; float f; } v; v.u = ((unsigned)h) << 16; return v.f;
}

__device__ __forceinline__ void gload_lds16(const void* g, void* l) {
  __builtin_amdgcn_global_load_lds((const __attribute__((address_space(1))) void*)g,
                                   (__attribute__((address_space(3))) void*)l, 16, 0, 0);
}

// ---------------- prep kernels ----------------

__global__ void k_zero(u16x8* __restrict__ p, int n8) {
  int i = blockIdx.x * blockDim.x + threadIdx.x;
  int stride = gridDim.x * blockDim.x;
  u16x8 z = (u16x8)0;
  for (; i < n8; i += stride) p[i] = z;
}

__global__ void k_cvt_x(const float* __restrict__ in, u16* __restrict__ out, int n4) {
  int i = blockIdx.x * blockDim.x + threadIdx.x;
  int stride = gridDim.x * blockDim.x;
  const f32x4* in4 = (const f32x4*)in;
  u16x4* out4 = (u16x4*)out;
  for (; i < n4; i += stride) {
    f32x4 v = in4[i];
    u16x4 o;
    o[0] = f2bf(v[0]); o[1] = f2bf(v[1]); o[2] = f2bf(v[2]); o[3] = f2bf(v[3]);
    out4[i] = o;
  }
}

// LDS-tiled transpose: w [K][1024] f32 -> outT [1024][K] bf16, 64x64 tiles.
__global__ void k_prep_wt(const float* __restrict__ wq, const float* __restrict__ wo,
                          const float* __restrict__ wk, const float* __restrict__ wv,
                          u16* __restrict__ WQ1T, u16* __restrict__ WO1T,
                          u16* __restrict__ WK1T, u16* __restrict__ WV1T) {
  __shared__ u16 tile[64][72];
  int bid = blockIdx.x;
  const float* w; u16* o; int K;
  if (bid < 256)      { w = wq; o = WQ1T; K = 1024; }
  else if (bid < 512) { w = wo; o = WO1T; K = 1024; bid -= 256; }
  else if (bid < 704) { w = wk; o = WK1T; K = 768;  bid -= 512; }
  else                { w = wv; o = WV1T; K = 768;  bid -= 704; }
  const int ti = bid >> 4, tj = bid & 15;
  const int t = threadIdx.x;
  const int r = t >> 2, cq = (t & 3) * 16;

  const float* src = w + (size_t)(ti * 64 + r) * 1024 + tj * 64 + cq;
#pragma unroll
  for (int j4 = 0; j4 < 4; ++j4) {
    f32x4 v = *(const f32x4*)(src + j4 * 4);
#pragma unroll
    for (int e = 0; e < 4; ++e) tile[r][cq + j4 * 4 + e] = f2bf(v[e]);
  }
  __syncthreads();

  u16 vals[16];
#pragma unroll
  for (int j = 0; j < 16; ++j) vals[j] = tile[cq + j][r];
  u16* dst = o + (size_t)(tj * 64 + r) * K + ti * 64 + cq;
  *(u16x8*)dst = *(u16x8*)&vals[0];
  *(u16x8*)(dst + 8) = *(u16x8*)&vals[8];
}

// y [1232][768] f32 -> yb bf16 (straight cvt)
__global__ void k_prep_y(const float* __restrict__ y, u16* __restrict__ yb, int n4) {
  int i = blockIdx.x * blockDim.x + threadIdx.x;
  int stride = gridDim.x * blockDim.x;
  const f32x4* in4 = (const f32x4*)y;
  u16x4* out4 = (u16x4*)yb;
  for (; i < n4; i += stride) {
    f32x4 v = in4[i];
    u16x4 o;
    o[0] = f2bf(v[0]); o[1] = f2bf(v[1]); o[2] = f2bf(v[2]); o[3] = f2bf(v[3]);
    out4[i] = o;
  }
}

// ---------------- K+V projections, merged, m97-style 128^2 ----------------
__global__ __launch_bounds__(256, 2) void k_gemm_kv(
    const u16* __restrict__ A,
    const u16* __restrict__ BK1, const float* __restrict__ bkb, u16* __restrict__ KTo,
    const u16* __restrict__ BV1, const float* __restrict__ bvb, u16* __restrict__ VTo)
{
  const int M = 1232, Kdim = 768;
  __shared__ u16 sA[128 * 32];
  __shared__ u16 sB[128 * 32];
  const int t = threadIdx.x;
  const int half = blockIdx.x >= 80;
  const int bb = blockIdx.x - half * 80;
  const u16* B = half ? BV1 : BK1;
  const float* bias = half ? bvb : bkb;
  u16* outp = half ? VTo : KTo;
  const int bm = bb / 8, bn = bb % 8;
  const int m0 = bm * 128, n0 = bn * 128;
  const int l = t & 63, wv_ = t >> 6;
  const int lr = l & 15, lg = l >> 4;
  const int wm = (wv_ >> 1) * 64, wn = (wv_ & 1) * 64;

  const int srow = t >> 2;
  const int ssw = ((t >> 2) & 3) ^ ((t >> 4) & 3);
  const int scol = ((t & 3) ^ ssw) * 8;
  char* ldsA = (char*)sA;
  char* ldsB = (char*)sB;
  const int ldsoff = wv_ * 1024;

  const int swl = (lr & 3) ^ ((lr >> 2) & 3);
  const int rds = (lg ^ swl) * 8;

  f32x4 acc[4][4] = {};

  for (int kt = 0; kt < Kdim / 32; ++kt) {
    const int k0 = kt * 32;
    __syncthreads();
    {
      int r1 = m0 + srow;       if (r1 > M - 1) r1 = M - 1;
      int r2 = m0 + 64 + srow;  if (r2 > M - 1) r2 = M - 1;
      gload_lds16(A + (size_t)r1 * Kdim + k0 + scol, ldsA + 0    + ldsoff);
      gload_lds16(A + (size_t)r2 * Kdim + k0 + scol, ldsA + 4096 + ldsoff);
      gload_lds16(B + (size_t)(n0 + srow) * Kdim + k0 + scol,      ldsB + 0    + ldsoff);
      gload_lds16(B + (size_t)(n0 + 64 + srow) * Kdim + k0 + scol, ldsB + 4096 + ldsoff);
    }
    __syncthreads();
    bf16x8 af[4], bfr[4];
#pragma unroll
    for (int mt = 0; mt < 4; ++mt)
      af[mt] = *(const bf16x8*)&sA[(wm + mt * 16 + lr) * 32 + rds];
#pragma unroll
    for (int nt = 0; nt < 4; ++nt)
      bfr[nt] = *(const bf16x8*)&sB[(wn + nt * 16 + lr) * 32 + rds];
#pragma unroll
    for (int mt = 0; mt < 4; ++mt)
#pragma unroll
      for (int nt = 0; nt < 4; ++nt)
        acc[mt][nt] = __builtin_amdgcn_mfma_f32_16x16x32_bf16(af[mt], bfr[nt], acc[mt][nt], 0, 0, 0);
  }

#pragma unroll
  for (int mt = 0; mt < 4; ++mt) {
#pragma unroll
    for (int nt = 0; nt < 4; ++nt) {
      const int gc = n0 + wn + nt * 16 + lr;
      const float bb2 = bias[gc];
#pragma unroll
      for (int r = 0; r < 4; ++r) {
        const int gr = m0 + wm + mt * 16 + lg * 4 + r;
        const float v = acc[mt][nt][r] + bb2;
        if (gr < M) {
          int bI = gr / 77, s = gr - bI * 77;
          int hh = gc >> 6, d = gc & 63;
          if (!half)
            outp[(((size_t)bI * 16 + hh) * 96 + s) * 64 + d] = f2bf(v);
          else
            outp[(((size_t)bI * 16 + hh) * 64 + d) * 96 + s] = f2bf(v);
        }
      }
    }
  }
}

// ---------------- big GEMM: 256x256, BK=64, 4-phase/tile counted-vmcnt pipeline ----------------
// M=65536, N=1024, K=1024. A [M][1024] bf16, B^T [1024][1024] bf16. 512 thr = 8 waves
// (2M x 4N), wave tile 128x64, 16 K-tiles. LDS 128KB = 2 dbuf x (A 32KB + B 32KB).
// sw16 swizzle (r5/r13: 0 bank conflicts; 128B rows, LDS slot = global slot ^ (row&7)).
// LOAD-GRANULARITY LEDGER (the r4/r7 fix): 8 stage-loads/tile (A j=0..3: 64 rows each;
// B j=0..3). Every wave reads its own 64 B-rows in EVERY phase -> B must land by tile
// start; only A's halves defer (A{2wm} needed ph0, A{2wm+1} needed ph2).
// Stage during tile c for c+1: ph0:(B0,B1) ph1:(A0,A2) ph2:(B2,B3) ph3:(A1,A3).
// Waits (before barriers): end-ph1 vmcnt(4) retires (A1,A3)(c) [3-phase cover];
// end-ph3 vmcnt(2) retires all of c+1 except (A1,A3) [B L2 ~300cyc, 2-phase cover;
// A0,A2 HBM ~900cyc, 3-phase ~1800cyc cover]. Induction: after boundary, outstanding
// = exactly (A1,A3)(c+1). Phases (mh-major): ph0=(mh0,kk0) ph1=(mh0,kk1) ph2=(mh1,kk0)
// ph3=(mh1,kk1); 16 MFMA each; B(kk) frags read once, reused across mh phases.
// EPI 0: fused attention epilogue (r14, verbatim). EPI 1: +bias -> f32.
template <int EPI>
__global__ __launch_bounds__(512, 2) void gemm8p(
    const u16* __restrict__ A, const u16* __restrict__ Bp,
    const float* __restrict__ bias, void* __restrict__ outp,
    const u16* __restrict__ KT, const u16* __restrict__ VT)
{
  __shared__ char lds[131072];
  const int t = threadIdx.x;
  const int cpx = (int)gridDim.x >> 3;
  const int swz = ((int)blockIdx.x & 7) * cpx + ((int)blockIdx.x >> 3);
  const int bm = swz >> 2, bn = swz & 3;
  const int m0 = bm * 256, n0 = bn * 256;
  const int w = t >> 6, l = t & 63, lr = l & 15, lg = l >> 4;
  const int wm = w >> 2, wn = w & 3;   // 2 M-waves x 4 N-waves, wave tile 128x64

  // staging: one gload covers 64 rows x 128B; thread t -> row t>>3, 16B slot t&7;
  // global k pre-swizzled so LDS[row][s] = global slot s ^ (row&7)
  const int srow = t >> 3;
  const int scol = ((t & 7) ^ ((t >> 3) & 7)) << 3;   // elems
  // read-side: slot (kk*4+lg) ^ (lr&7)  (frag rows have row&7 == lr&7)
  const int sw0 = ((lg) ^ (lr & 7)) << 4;
  const int sw1 = ((4 + lg) ^ (lr & 7)) << 4;
  const int abase = wm * 128 + lr;
  const int bbase = wn * 64 + lr;

  f32x4 acc[8][4] = {};

#define RD_A(dst, db, mh, ksw) { _Pragma("unroll") for (int q = 0; q < 4; ++q) \
    dst[q] = *(const bf16x8*)(lds + (db) + ((abase + (mh) * 64 + q * 16) << 7) + (ksw)); }
#define RD_B(dst, db, ksw) { _Pragma("unroll") for (int nt = 0; nt < 4; ++nt) \
    dst[nt] = *(const bf16x8*)(lds + (db) + 32768 + ((bbase + nt * 16) << 7) + (ksw)); }
#define STG_A(kt, dn, j) gload_lds16(A + (size_t)(m0 + (j) * 64 + srow) * 1024 + (kt) * 64 + scol, \
                                     lds + (dn) + (j) * 8192 + t * 16)
#define STG_B(kt, dn, j) gload_lds16(Bp + (size_t)(n0 + (j) * 64 + srow) * 1024 + (kt) * 64 + scol, \
                                     lds + (dn) + 32768 + (j) * 8192 + t * 16)
#define MM16(ab, a_, b_) { __builtin_amdgcn_s_setprio(1); \
  _Pragma("unroll") for (int q = 0; q < 4; ++q) \
    _Pragma("unroll") for (int nt = 0; nt < 4; ++nt) \
      acc[(ab) + q][nt] = __builtin_amdgcn_mfma_f32_16x16x32_bf16(a_[q], b_[nt], acc[(ab) + q][nt], 0, 0, 0); \
  __builtin_amdgcn_s_setprio(0); }
#define BAR __builtin_amdgcn_s_barrier()
#define SB0 __builtin_amdgcn_sched_barrier(0)
#define VM2 asm volatile("s_waitcnt vmcnt(2)" ::: "memory")
#define VM4 asm volatile("s_waitcnt vmcnt(4)" ::: "memory")

  // prologue: stage tile 0 in ledger order; vmcnt(2) leaves (A1,A3)(t0) flying.
  STG_B(0, 0, 0); STG_B(0, 0, 1);
  STG_A(0, 0, 0); STG_A(0, 0, 2);
  STG_B(0, 0, 2); STG_B(0, 0, 3);
  STG_A(0, 0, 1); STG_A(0, 0, 3);
  VM2; SB0; BAR;

#pragma unroll 2
  for (int c = 0; c < 16; ++c) {
    const int db = (c & 1) * 65536, dn = db ^ 65536;
    int cn = c + 1; if (cn > 15) cn = 15;   // tail: dummy re-stage of t15 into dead buf
    bf16x8 a_[4], b0[4], b1[4];
    // ph0: (mh0, kk0); stage B0,B1(c+1)
    RD_A(a_, db, 0, sw0); RD_B(b0, db, sw0);
    STG_B(cn, dn, 0); STG_B(cn, dn, 1);
    BAR;
    MM16(0, a_, b0);
    BAR;
    // ph1: (mh0, kk1); stage A0,A2(c+1); vmcnt(4) retires (A1,A3)(c) before ph2 reads
    RD_A(a_, db, 0, sw1); RD_B(b1, db, sw1);
    STG_A(cn, dn, 0); STG_A(cn, dn, 2);
    VM4; SB0; BAR;
    MM16(0, a_, b1);
    BAR;
    // ph2: (mh1, kk0) -- b0 reused; stage B2,B3(c+1)
    RD_A(a_, db, 1, sw0);
    STG_B(cn, dn, 2); STG_B(cn, dn, 3);
    BAR;
    MM16(4, a_, b0);
    BAR;
    // ph3: (mh1, kk1); stage A1,A3(c+1); boundary vmcnt(2)
    RD_A(a_, db, 1, sw1);
    STG_A(cn, dn, 1); STG_A(cn, dn, 3);
    VM2; SB0; BAR;
    MM16(4, a_, b1);
    BAR;
  }
  asm volatile("s_waitcnt vmcnt(0)" ::: "memory");  // drain dummy stages
  SB0; BAR;                                          // LDS quiescent block-wide

#undef RD_A
#undef RD_B
#undef STG_A
#undef STG_B
#undef MM16
#undef BAR
#undef SB0
#undef VM2
#undef VM4

  if constexpr (EPI == 1) {
    // out-proj epilogue: +bias -> f32
#pragma unroll
    for (int q = 0; q < 8; ++q) {
#pragma unroll
      for (int nt = 0; nt < 4; ++nt) {
        const int gc = n0 + wn * 64 + nt * 16 + lr;
        const float bb = bias[gc];
#pragma unroll
        for (int r = 0; r < 4; ++r) {
          const int gr = m0 + wm * 128 + q * 16 + lg * 4 + r;
          ((float*)outp)[(size_t)gr * 1024 + gc] = acc[q][nt][r] + bb;
        }
      }
    }
  } else {
    // ---- fused attention epilogue (r14, verbatim) ----
    const int hh = (n0 >> 6) + wn;
    const int b = m0 >> 12;
    const u16* gK = KT + (size_t)(b * 16 + hh) * (96 * 64);
    const u16* gV = VT + (size_t)(b * 16 + hh) * (64 * 96);
    u16* Qs = (u16*)(lds + w * 16384);
    u16* Ps = (u16*)(lds + w * 16384 + 8192);
    u16* QBo = (u16*)outp;

    bf16x8 fk[5][2], fv[4][3];
#pragma unroll
    for (int nt = 0; nt < 5; ++nt)
#pragma unroll
      for (int ks = 0; ks < 2; ++ks)
        fk[nt][ks] = *(const bf16x8*)&gK[(nt * 16 + lr) * 64 + ks * 32 + lg * 8];
#pragma unroll
    for (int nt = 0; nt < 4; ++nt)
#pragma unroll
      for (int ks = 0; ks < 3; ++ks)
        fv[nt][ks] = *(const bf16x8*)&gV[(nt * 16 + lr) * 96 + ks * 32 + lg * 8];

    float bb[4];
#pragma unroll
    for (int nt = 0; nt < 4; ++nt) bb[nt] = bias[n0 + wn * 64 + nt * 16 + lr];

#pragma unroll
    for (int cc = 0; cc < 4; ++cc) {
#pragma unroll
      for (int qq = 0; qq < 2; ++qq)
#pragma unroll
        for (int nt = 0; nt < 4; ++nt)
#pragma unroll
          for (int r = 0; r < 4; ++r)
            Qs[(qq * 16 + lg * 4 + r) * 72 + nt * 16 + lr] =
                f2bf(acc[cc * 2 + qq][nt][r] + bb[nt]);

      bf16x8 aq[2][2];
#pragma unroll
      for (int qq = 0; qq < 2; ++qq)
#pragma unroll
        for (int ks = 0; ks < 2; ++ks)
          aq[qq][ks] = *(const bf16x8*)&Qs[(qq * 16 + lr) * 72 + ks * 32 + lg * 8];

      f32x4 s_[2][5] = {};
#pragma unroll
      for (int nt = 0; nt < 5; ++nt)
#pragma unroll
        for (int ks = 0; ks < 2; ++ks)
#pragma unroll
          for (int qq = 0; qq < 2; ++qq)
            s_[qq][nt] = __builtin_amdgcn_mfma_f32_16x16x32_bf16(aq[qq][ks], fk[nt][ks], s_[qq][nt], 0, 0, 0);
#pragma unroll
      for (int qq = 0; qq < 2; ++qq)
#pragma unroll
        for (int nt = 0; nt < 5; ++nt)
#pragma unroll
          for (int r = 0; r < 4; ++r)
            s_[qq][nt][r] *= 0.125f;
      if (lr >= 13) {
#pragma unroll
        for (int qq = 0; qq < 2; ++qq)
#pragma unroll
          for (int r = 0; r < 4; ++r)
            s_[qq][4][r] = -1e30f;
      }

      float ri[2][4];
#pragma unroll
      for (int qq = 0; qq < 2; ++qq) {
#pragma unroll
        for (int r = 0; r < 4; ++r) {
          float m1 = s_[qq][0][r];
#pragma unroll
          for (int nt = 1; nt < 5; ++nt) m1 = fmaxf(m1, s_[qq][nt][r]);
          m1 = fmaxf(m1, __shfl_xor(m1, 1, 64));
          m1 = fmaxf(m1, __shfl_xor(m1, 2, 64));
          m1 = fmaxf(m1, __shfl_xor(m1, 4, 64));
          m1 = fmaxf(m1, __shfl_xor(m1, 8, 64));
          float s1 = 0.f;
#pragma unroll
          for (int nt = 0; nt < 5; ++nt) {
            float e = __expf(s_[qq][nt][r] - m1);
            s_[qq][nt][r] = e;
            s1 += e;
          }
          s1 += __shfl_xor(s1, 1, 64);
          s1 += __shfl_xor(s1, 2, 64);
          s1 += __shfl_xor(s1, 4, 64);
          s1 += __shfl_xor(s1, 8, 64);
          ri[qq][r] = 1.0f / s1;
        }
      }

#pragma unroll
      for (int qq = 0; qq < 2; ++qq)
#pragma unroll
        for (int nt = 0; nt < 5; ++nt)
#pragma unroll
          for (int r = 0; r < 4; ++r)
            Ps[(qq * 16 + lg * 4 + r) * 104 + nt * 16 + lr] = f2bf(s_[qq][nt][r] * ri[qq][r]);
#pragma unroll
      for (int qq = 0; qq < 2; ++qq)
#pragma unroll
        for (int r = 0; r < 4; ++r)
          Ps[(qq * 16 + lg * 4 + r) * 104 + 80 + lr] = 0;

      f32x4 o_[2][4] = {};
#pragma unroll
      for (int ks = 0; ks < 3; ++ks) {
        bf16x8 ap[2];
#pragma unroll
        for (int qq = 0; qq < 2; ++qq)
          ap[qq] = *(const bf16x8*)&Ps[(qq * 16 + lr) * 104 + ks * 32 + lg * 8];
#pragma unroll
        for (int nt = 0; nt < 4; ++nt)
#pragma unroll
          for (int qq = 0; qq < 2; ++qq)
            o_[qq][nt] = __builtin_amdgcn_mfma_f32_16x16x32_bf16(ap[qq], fv[nt][ks], o_[qq][nt], 0, 0, 0);
      }

#pragma unroll
      for (int qq = 0; qq < 2; ++qq)
#pragma unroll
        for (int nt = 0; nt < 4; ++nt)
#pragma unroll
          for (int r = 0; r < 4; ++r)
            QBo[(size_t)(m0 + wm * 128 + cc * 32 + qq * 16 + lg * 4 + r) * 1024
                + hh * 64 + nt * 16 + lr] = f2bf(o_[qq][nt][r]);
    }
  }
}

// ---------------- launch ----------------

extern "C" void kernel_launch(void* const* d_in, const int* in_sizes, int n_in,
                              void* d_out, int out_size, void* d_ws, size_t ws_size,
                              hipStream_t stream) {
  const float* x  = (const float*)d_in[0];
  const float* y  = (const float*)d_in[1];
  const float* wq = (const float*)d_in[2];
  const float* bq = (const float*)d_in[3];
  const float* wk = (const float*)d_in[4];
  const float* bk = (const float*)d_in[5];
  const float* wv = (const float*)d_in[6];
  const float* bv = (const float*)d_in[7];
  const float* wo = (const float*)d_in[8];
  const float* bo = (const float*)d_in[9];

  char* ws = (char*)d_ws;
  u16* QB   = (u16*)(ws + 0);            // 65536x1024 bf16 = 128 MB (attn-out)
  u16* WQ1T = (u16*)(ws + 134217728);    // [1024][1024] bf16, 2 MB
  u16* WO1T = (u16*)(ws + 136314880);    // 2 MB
  u16* WK1T = (u16*)(ws + 138412032);    // [1024][768] bf16, 1.5 MB
  u16* WV1T = (u16*)(ws + 139984896);    // 1.5 MB
  u16* YB   = (u16*)(ws + 141557760);    // [1232][768] bf16, 1.85 MB
  u16* KT   = (u16*)(ws + 143654912);    // [16][16][96][64] bf16, 3 MB
  u16* VT   = (u16*)(ws + 146800640);    // [16][16][64][96] bf16, 3 MB

  u16*   XB  = (u16*)d_out;   // x as bf16, first 128 MB of d_out (consumed before final write)
  float* OUT = (float*)d_out;

  // prep
  k_zero<<<768, 256, 0, stream>>>((u16x8*)KT, 393216);          // zero KT+VT (adjacent, 6 MB)
  k_cvt_x<<<4096, 256, 0, stream>>>(x, XB, 16777216);
  k_prep_wt<<<896, 256, 0, stream>>>(wq, wo, wk, wv, WQ1T, WO1T, WK1T, WV1T);
  k_prep_y<<<924, 256, 0, stream>>>(y, YB, 236544);

  // K+V projections (one launch): M=1232, K=768
  k_gemm_kv<<<160, 256, 0, stream>>>(YB, WK1T, bk, KT, WV1T, bv, VT);

  // Q projection + FUSED ATTENTION -> QB
  gemm8p<0><<<1024, 512, 0, stream>>>(XB, WQ1T, bq, QB, KT, VT);

  // output projection -> f32 d_out
  gemm8p<1><<<1024, 512, 0, stream>>>(QB, WO1T, bo, OUT, nullptr, nullptr);
}